// Round 14
// baseline (1631.923 us; speedup 1.0000x reference)
//
#include <hip/hip_runtime.h>
#include <hip/hip_bf16.h>

typedef _Float16 h2 __attribute__((ext_vector_type(2)));
typedef _Float16 h8 __attribute__((ext_vector_type(8)));
typedef __attribute__((ext_vector_type(4))) float floatx4;

#define NEGF 1.0e12f

#if __has_builtin(__builtin_amdgcn_fdot2)
#define DOT2(a,b,c) __builtin_amdgcn_fdot2((a),(b),(c),false)
#else
static __device__ __forceinline__ float DOT2(h2 a, h2 b, float c){
  return c + (float)a[0]*(float)b[0] + (float)a[1]*(float)b[1];
}
#endif

__device__ __forceinline__ float dot8(h8 a, h8 b, float c){
  h2 a0 = {a[0],a[1]}, a1 = {a[2],a[3]}, a2 = {a[4],a[5]}, a3 = {a[6],a[7]};
  h2 b0 = {b[0],b[1]}, b1 = {b[2],b[3]}, b2 = {b[4],b[5]}, b3 = {b[6],b[7]};
  c = DOT2(a0,b0,c); c = DOT2(a1,b1,c); c = DOT2(a2,b2,c); c = DOT2(a3,b3,c);
  return c;
}

__device__ __forceinline__ unsigned f16bits(float x){
  union { _Float16 h; unsigned short u; } cv; cv.h = (_Float16)x; return (unsigned)cv.u;
}
__device__ __forceinline__ unsigned f32bits(float x){
  union { float f; unsigned u; } cv; cv.f = x; return cv.u;
}
__device__ __forceinline__ float bits32f(unsigned u){
  union { unsigned u; float f; } cv; cv.u = u; return cv.f;
}

#define GLD_LDS16(g, l) __builtin_amdgcn_global_load_lds( \
    (const __attribute__((address_space(1))) void*)(g),   \
    (__attribute__((address_space(3))) void*)(l), 16, 0, 0)

#define ALOAD64(p)    __hip_atomic_load((p), __ATOMIC_RELAXED, __HIP_MEMORY_SCOPE_AGENT)
#define ALOAD32(p)    __hip_atomic_load((p), __ATOMIC_RELAXED, __HIP_MEMORY_SCOPE_AGENT)
#define ASTORE32(p,v) __hip_atomic_store((p), (v), __ATOMIC_RELAXED, __HIP_MEMORY_SCOPE_AGENT)

// ---------------- generic f16 MFMA GEMM: C[M,N] = A[M,K] @ B[N,K]^T ----------------
template<int EPI>
__global__ __launch_bounds__(256) void gemm_f16(
    const _Float16* __restrict__ A, const _Float16* __restrict__ B,
    float* __restrict__ Cf, _Float16* __restrict__ Ch,
    const float* __restrict__ bias, int N, int K, int ldc, int ntn)
{
  __shared__ char smem[32768];
  _Float16* Al = (_Float16*)smem;
  _Float16* Bl = (_Float16*)(smem + 16384);
  int bid = blockIdx.x;
  int bn = bid % ntn, bm = bid / ntn;
  int t = threadIdx.x;
  int w = t >> 6, l = t & 63;

  floatx4 acc[4][4];
#pragma unroll
  for (int i = 0; i < 4; ++i)
#pragma unroll
    for (int j = 0; j < 4; ++j) acc[i][j] = (floatx4){0.f, 0.f, 0.f, 0.f};

  const char* Ab = (const char*)A + (size_t)bm * 128 * K * 2;
  const char* Bb = (const char*)B + (size_t)bn * 128 * K * 2;
  const int rowb = K * 2;
  const int r0 = t >> 3;
  const int cbyte = ((t & 7) * 16) ^ (((t >> 3) & 7) << 4);
  char* AlB = (char*)Al;
  char* BlB = (char*)Bl;
  const int wm = (w >> 1) * 64, wn = (w & 1) * 64;

  for (int kt = 0; kt < K; kt += 64) {
    __syncthreads();
#pragma unroll
    for (int c = 0; c < 4; ++c) {
      int row = c * 32 + r0;
      GLD_LDS16(Ab + (size_t)row * rowb + kt * 2 + cbyte, AlB + c * 4096 + t * 16);
      GLD_LDS16(Bb + (size_t)row * rowb + kt * 2 + cbyte, BlB + c * 4096 + t * 16);
    }
    __syncthreads();
#pragma unroll
    for (int kk = 0; kk < 64; kk += 32) {
      h8 af[4], bfv[4];
#pragma unroll
      for (int i = 0; i < 4; ++i) {
        int ra = wm + i * 16 + (l & 15);
        int cb = ((kk << 1) + ((l >> 4) << 4)) ^ ((ra & 7) << 4);
        af[i] = *(const h8*)(AlB + ra * 128 + cb);
      }
#pragma unroll
      for (int j = 0; j < 4; ++j) {
        int ra = wn + j * 16 + (l & 15);
        int cb = ((kk << 1) + ((l >> 4) << 4)) ^ ((ra & 7) << 4);
        bfv[j] = *(const h8*)(BlB + ra * 128 + cb);
      }
#pragma unroll
      for (int i = 0; i < 4; ++i)
#pragma unroll
        for (int j = 0; j < 4; ++j)
          acc[i][j] = __builtin_amdgcn_mfma_f32_16x16x32_f16(af[i], bfv[j], acc[i][j], 0, 0, 0);
    }
  }

  if (EPI == 3) {
    float* Cs = (float*)smem;
#pragma unroll
    for (int half = 0; half < 2; ++half) {
      __syncthreads();
      if ((w >> 1) == half) {
        int rbase = ((l >> 4) << 2);
#pragma unroll
        for (int i = 0; i < 4; ++i)
#pragma unroll
          for (int j = 0; j < 4; ++j)
#pragma unroll
            for (int r = 0; r < 4; ++r)
              Cs[(i * 16 + rbase + r) * 128 + wn + j * 16 + (l & 15)] = acc[i][j][r];
      }
      __syncthreads();
#pragma unroll
      for (int rr = 0; rr < 16; ++rr) {
        int row = rr * 4 + w;
        int grow = bm * 128 + half * 64 + row;
        int cc = bn * 128 + 2 * l;
        float2 v = *(float2*)&Cs[row * 128 + 2 * l];
        float vv0, vv1;
        if (cc < N)     { float x0 = v.x + bias[cc];     vv0 = (x0 == 0.f) ? -NEGF : x0; } else vv0 = -NEGF;
        if (cc + 1 < N) { float x1 = v.y + bias[cc + 1]; vv1 = (x1 == 0.f) ? -NEGF : x1; } else vv1 = -NEGF;
        float* orow = Cf + (size_t)grow * ldc;
        if (cc + 1 < ldc) { float2 o; o.x = vv0; o.y = vv1; *(float2*)(orow + cc) = o; }
        else if (cc < ldc) orow[cc] = vv0;
      }
    }
  } else {
    int mbase = bm * 128 + wm + ((l >> 4) << 2);
    int nbase = bn * 128 + wn + (l & 15);
#pragma unroll
    for (int j = 0; j < 4; ++j) {
      int col = nbase + j * 16;
#pragma unroll
      for (int i = 0; i < 4; ++i) {
#pragma unroll
        for (int r = 0; r < 4; ++r) {
          int row = mbase + i * 16 + r;
          float v = acc[i][j][r];
          if (col < N) {
            float bv = bias ? bias[col] : 0.f;
            if (EPI == 0)      Cf[(size_t)row * ldc + col] = v + bv;
            else if (EPI == 1) Ch[(size_t)row * ldc + col] = (_Float16)(v + bv);
            else               Ch[(size_t)row * ldc + col] = (_Float16)tanhf(v + bv);
          }
        }
      }
    }
  }
}

// ---------------- cast / pad kernels ----------------
__global__ void cast_pad_kernel(const float* __restrict__ src, _Float16* __restrict__ dst,
                                int R, int C, int ld_src, int Cpad, int ld_dst, long total){
  long i = (long)blockIdx.x * 256 + threadIdx.x;
  if (i >= total) return;
  int r = (int)(i / Cpad), c = (int)(i % Cpad);
  float v = (r < R && c < C) ? src[(size_t)r * ld_src + c] : 0.f;
  dst[(size_t)r * ld_dst + c] = (_Float16)v;
}

__global__ void cast_emb_kernel(const float* __restrict__ trg, _Float16* __restrict__ dst){
  int i = blockIdx.x * 256 + threadIdx.x;
  if (i >= 1024 * 320) return;
  int m = i / 320, e = i % 320;
  int tt = m >> 5, b = m & 31;
  float v = (e < 300) ? trg[((size_t)b * 32 + tt) * 300 + e] : 0.f;
  dst[i] = (_Float16)v;
}

__global__ void cast_wr2t_kernel(const float* __restrict__ wred, _Float16* __restrict__ dst){
  int i = blockIdx.x * 256 + threadIdx.x;
  if (i >= 512 * 320) return;
  int h = i / 320, e = i % 320;
  float v = (e < 300) ? wred[(size_t)e * 812 + 300 + h] : 0.f;
  dst[i] = (_Float16)v;
}

// HCzT slab: unit u = kc*32 + b (16B each), holds z[b][kc*8 .. kc*8+8]
__global__ void init_kernel(const float* __restrict__ h0, const float* __restrict__ b_ih,
                            const float* __restrict__ b_hh,
                            _Float16* __restrict__ HCzT, float* __restrict__ bias_sum,
                            _Float16* __restrict__ X1h, unsigned* __restrict__ bar){
  int i = blockIdx.x * 256 + threadIdx.x;
  if (i < 32768) {
    int unit = i >> 3, pos = i & 7;
    int kc = unit >> 5, b = unit & 31;
    int k = kc * 8 + pos;
    HCzT[i] = (k < 512) ? (_Float16)h0[b * 512 + k] : (_Float16)0.f;
  }
  if (i < 2048)  bias_sum[i] = b_ih[i] + b_hh[i];
  if (i < 327680) X1h[i] = (_Float16)0.f;
  if (i < 1024) bar[i] = 0u;
}

// ---------------- fence-free flag barrier over 64 blocks (R12-proven pattern) ----------------
__device__ __forceinline__ void gbar(unsigned* flags, unsigned gen){
  asm volatile("s_waitcnt vmcnt(0)" ::: "memory");   // drain this wave's bypass stores
  __syncthreads();
  if (threadIdx.x == 0) {
    ASTORE32(flags + blockIdx.x, gen);               // independent arrival store (no RMW)
    for (;;) {
      bool done = true;
#pragma unroll
      for (int i = 0; i < 64; ++i)
        done &= (ALOAD32(flags + i) >= gen);
      if (done) break;
      __builtin_amdgcn_s_sleep(2);
    }
  }
  __syncthreads();
  asm volatile("" ::: "memory");
}

// ---------------- fused persistent recurrence: 64 blocks x 512 threads ----------------
// Pair (2q, 2q+1) shares batch q. Phase A: gates j-slice qb*16, batch-half hf, MFMA.
// B1: energy s-half (200 rows). B2: softmax (redundant) + context d-half (256 cols).
__global__ __launch_bounds__(512, 1) void fused_loop(
    const _Float16* __restrict__ memh, _Float16* __restrict__ HCzT,
    _Float16* __restrict__ HC_A, const _Float16* __restrict__ Wz,
    const float* __restrict__ P, const float* __restrict__ inits,
    const int* __restrict__ mask, float* __restrict__ e_out,
    float* __restrict__ a_out, float* __restrict__ c_out,
    unsigned* __restrict__ bar, unsigned* __restrict__ ES)
{
  __shared__ float gl[32 * 256];                // 32 KB partial gate sums
  __shared__ __align__(16) float es[400];       // normalized attn (B2)
  __shared__ float red[16];
  __shared__ float cum[400];
  __shared__ _Float16 hh[512];
  __shared__ float part[256];

  const int blk = blockIdx.x, t = threadIdx.x;
  const int qb = blk >> 1, hf = blk & 1;
  const int w = t >> 6, l = t & 63;
  const int nw = w;                              // k-eighth (8 waves)

  if (t < 400) cum[t] = 0.f;

  float creg = 0.f;
  if (t < 256) creg = inits[(hf * 16 + (t >> 4)) * 512 + qb * 16 + (t & 15)];   // c0 = h0
  const _Float16* mb = memh + (size_t)qb * 400 * 512;

  // per-gate weight row base (L2-resident); wave nw covers k-cols nw*128 .. +127
  const _Float16* wbase[4];
#pragma unroll
  for (int s = 0; s < 4; ++s)
    wbase[s] = Wz + (size_t)(s * 512 + qb * 16 + (l & 15)) * 1024 + nw * 128 + ((l >> 4) << 3);

  __syncthreads();

  for (int ts = 0; ts < 32; ++ts) {
    // ======== phase A: gates MFMA (j-slice qb*16, batches hf*16.., k split 8 waves) ========
    {
      unsigned long long* zsrc = (unsigned long long*)(HCzT + (size_t)ts * 32768);
      floatx4 acc[4];
#pragma unroll
      for (int s = 0; s < 4; ++s) acc[s] = (floatx4){0.f, 0.f, 0.f, 0.f};
#pragma unroll
      for (int kk8 = 0; kk8 < 4; ++kk8) {
        int unit = ((nw * 4 + kk8) * 4 + (l >> 4)) * 32 + hf * 16 + (l & 15);
        union { unsigned long long u[2]; h8 v; } za;
        za.u[0] = ALOAD64(zsrc + (size_t)unit * 2);
        za.u[1] = ALOAD64(zsrc + (size_t)unit * 2 + 1);
#pragma unroll
        for (int s = 0; s < 4; ++s) {
          h8 wv = *(const h8*)(wbase[s] + kk8 * 32);
          acc[s] = __builtin_amdgcn_mfma_f32_16x16x32_f16(za.v, wv, acc[s], 0, 0, 0);
        }
      }
#pragma unroll
      for (int s = 0; s < 4; ++s)
#pragma unroll
        for (int r = 0; r < 4; ++r) {
          int b16 = ((l >> 4) << 2) + r;
          int idx = (b16 * 16 + (l & 15)) ^ (((b16 >> 2) & 1) << 4);   // bank swizzle
          gl[(s * 8 + nw) * 256 + idx] = acc[s][r];
        }
    }
    __syncthreads();
    // ---- LSTM pointwise: thread t<256 -> (b16 = t>>4, j16 = t&15), batch hf*16+b16 ----
    if (t < 256) {
      int b16 = t >> 4, j16 = t & 15;
      int b = hf * 16 + b16;
      int tsw = t ^ (((t >> 6) & 1) << 4);       // matching read swizzle
      const float* Pr = P + ((size_t)ts * 32 + b) * 2048 + qb * 16 + j16;
      float g4[4];
#pragma unroll
      for (int s = 0; s < 4; ++s) {
        float acc = 0.f;
#pragma unroll
        for (int k = 0; k < 8; ++k) acc += gl[(s * 8 + k) * 256 + tsw];
        g4[s] = acc + Pr[s * 512];
      }
      float ig = 1.f / (1.f + expf(-g4[0]));
      float fg = 1.f / (1.f + expf(-g4[1]));
      float og = 1.f / (1.f + expf(-g4[3]));
      float cn = fg * creg + ig * tanhf(g4[2]);
      float hn = og * tanhf(cn);
      creg = cn;
      unsigned hu = f16bits(hn);
      unsigned other = __shfl_xor(hu, 1);
      if (!(t & 1)) {
        unsigned pack = hu | (other << 16);
        int j = qb * 16 + j16;
        unsigned* dst = (unsigned*)((char*)(HCzT + (size_t)(ts + 1) * 32768)
                                    + (((j >> 3) * 32 + b) << 4) + ((j & 7) << 1));
        ASTORE32(dst, pack);
        *(unsigned*)(HC_A + ((size_t)ts * 32 + b) * 1024 + j) = pack;
      }
    }
    gbar(bar, 3 * ts + 1);

    // ======== phase B1: energy for batch qb, s-half hf ========
    size_t obase = (size_t)ts * 12800 + qb * 400;
    {
      if (t < 64) {
        unsigned long long* hsrc = (unsigned long long*)(HCzT + (size_t)(ts + 1) * 32768);
        union { unsigned long long u[2]; h8 v; } ha;
        ha.u[0] = ALOAD64(hsrc + ((size_t)t * 32 + qb) * 2);
        ha.u[1] = ALOAD64(hsrc + ((size_t)t * 32 + qb) * 2 + 1);
        *(h8*)&hh[t * 8] = ha.v;
      }
      __syncthreads();

      int g = l >> 2, c = l & 3;
#pragma unroll
      for (int r = 0; r < 2; ++r) {
        int sr = r * 16 + g;
        if (sr < 25) {
          int s = hf * 200 + w * 25 + sr;
          const _Float16* row = mb + (size_t)s * 512 + c * 128;
          float e = 0.f;
#pragma unroll
          for (int k = 0; k < 16; ++k)
            e = dot8(*(const h8*)(row + k * 8), *(const h8*)&hh[c * 128 + k * 8], e);
          e += __shfl_xor(e, 1);
          e += __shfl_xor(e, 2);
          if (c == 0) {
            if (mask[qb * 400 + s] == 0) e = -NEGF;
            e_out[obase + s] = e;
            ASTORE32(ES + qb * 400 + s, f32bits(e));
          }
        }
      }
    }
    gbar(bar, 3 * ts + 2);

    // ======== phase B2: softmax (full, redundant) + context d-half ========
    {
      float v = -3.4e38f;
      if (t < 400) v = bits32f(ALOAD32(ES + qb * 400 + t));
      float m = v;
#pragma unroll
      for (int o = 32; o; o >>= 1) m = fmaxf(m, __shfl_xor(m, o));
      if (l == 0) red[w] = m;
      __syncthreads();
      m = red[0];
#pragma unroll
      for (int qq = 1; qq < 8; ++qq) m = fmaxf(m, red[qq]);
      float p = (t < 400) ? expf(v - m) : 0.f;
      float sum = p;
#pragma unroll
      for (int o = 32; o; o >>= 1) sum += __shfl_xor(sum, o);
      if (l == 0) red[8 + w] = sum;
      __syncthreads();
      float tot = red[8];
#pragma unroll
      for (int qq = 9; qq < 16; ++qq) tot += red[qq];
      float inv = 1.f / tot;
      float aval = p * inv;
      if (t < 400) {
        es[t] = aval;
        if ((t >= hf * 200) && (t < hf * 200 + 200)) {   // own s-half outputs
          a_out[obase + t] = aval;
          c_out[obase + t] = cum[t];
          cum[t] += aval;
        }
      }
      __syncthreads();

      // context: d-half hf; 256 cols, rows split 2x200, 4 accumulators
      {
        int c2 = t & 255, rhalf = t >> 8;
        int d = hf * 256 + c2;
        int s0 = rhalf * 200;
        float a0 = 0.f, a1 = 0.f, a2 = 0.f, a3 = 0.f;
#pragma unroll 4
        for (int si = 0; si < 200; si += 4) {
          a0 += es[s0 + si + 0] * (float)mb[(size_t)(s0 + si + 0) * 512 + d];
          a1 += es[s0 + si + 1] * (float)mb[(size_t)(s0 + si + 1) * 512 + d];
          a2 += es[s0 + si + 2] * (float)mb[(size_t)(s0 + si + 2) * 512 + d];
          a3 += es[s0 + si + 3] * (float)mb[(size_t)(s0 + si + 3) * 512 + d];
        }
        float acc = (a0 + a1) + (a2 + a3);
        if (rhalf == 0) part[c2] = acc;
        __syncthreads();
        if (rhalf == 1) {
          float cv = part[c2] + acc;
          unsigned cu = f16bits(cv);
          unsigned other = __shfl_xor(cu, 1);
          if (!(c2 & 1)) {
            unsigned pack = cu | (other << 16);
            int kg = 512 + d;
            unsigned* dst = (unsigned*)((char*)(HCzT + (size_t)(ts + 1) * 32768)
                                        + (((kg >> 3) * 32 + qb) << 4) + ((kg & 7) << 1));
            ASTORE32(dst, pack);
            *(unsigned*)(HC_A + ((size_t)ts * 32 + qb) * 1024 + kg) = pack;
          }
        }
      }
    }
    gbar(bar, 3 * ts + 3);
  }
}

// ---------------- pointer scatter-max patch ----------------
__global__ __launch_bounds__(512) void pointer_kernel(
    const int* __restrict__ ext, const float* __restrict__ energ, float* __restrict__ logits)
{
  __shared__ int ids[400];
  __shared__ float es[400];
  int tb = blockIdx.x;
  int b = tb & 31;
  int tt = tb >> 5;
  int t = threadIdx.x;
  if (t < 400) {
    ids[t] = ext[b * 400 + t];
    es[t] = energ[(size_t)tt * 12800 + b * 400 + t];
  }
  __syncthreads();
  if (t < 400) {
    int id = ids[t];
    bool first = true;
    for (int s = 0; s < t; ++s) if (ids[s] == id) { first = false; break; }
    if (first) {
      float mx = es[t];
      for (int s = t + 1; s < 400; ++s) if (ids[s] == id) mx = fmaxf(mx, es[s]);
      if (mx != -NEGF) {
        float* p = &logits[(size_t)tb * 45050 + id];
        float base = 0.f;
        if (id < 45000) { float cur = *p; base = (cur == -NEGF) ? 0.f : cur; }
        float nv = base + mx;
        *p = (nv == 0.f) ? -NEGF : nv;
      }
    }
  }
}

// ---------------- host launcher ----------------
extern "C" void kernel_launch(void* const* d_in, const int* in_sizes, int n_in,
                              void* d_out, int out_size, void* d_ws, size_t ws_size,
                              hipStream_t stream) {
  const float* trg   = (const float*)d_in[0];
  const int*   ext   = (const int*)d_in[1];
  const float* inits = (const float*)d_in[2];
  const float* enc   = (const float*)d_in[3];
  const int*   mask  = (const int*)d_in[4];
  const float* W_enc = (const float*)d_in[5];
  const float* b_enc = (const float*)d_in[6];
  const float* W_red = (const float*)d_in[7];
  const float* b_red = (const float*)d_in[8];
  const float* W_ih  = (const float*)d_in[9];
  const float* W_hh  = (const float*)d_in[10];
  const float* b_ih  = (const float*)d_in[11];
  const float* b_hh  = (const float*)d_in[12];
  const float* W_cat = (const float*)d_in[13];
  const float* b_cat = (const float*)d_in[14];
  const float* W_log = (const float*)d_in[15];
  const float* b_log = (const float*)d_in[16];

  float* out = (float*)d_out;
  float* out_logits = out;                       // [1024 x 45050]
  float* out_attn   = out + 46131200;
  float* out_cov    = out_attn + 409600;
  float* out_energy = out_cov + 409600;

  char* ws = (char*)d_ws;
  size_t o = 0;
  auto alloc = [&](size_t bytes) { void* p = ws + o; o += (bytes + 255) & ~(size_t)255; return p; };
  _Float16* mem_h   = (_Float16*)alloc(12800ULL * 512 * 2);
  _Float16* enc_h   = (_Float16*)alloc(12800ULL * 512 * 2);
  _Float16* W_enc_h = (_Float16*)alloc(512ULL * 512 * 2);
  _Float16* emb_h   = (_Float16*)alloc(1024ULL * 320 * 2);
  _Float16* Wr1_h   = (_Float16*)alloc(384ULL * 320 * 2);
  _Float16* X1_h    = (_Float16*)alloc(1024ULL * 320 * 2);
  _Float16* W_ih_h  = (_Float16*)alloc(2048ULL * 320 * 2);
  _Float16* Wr2T_h  = (_Float16*)alloc(512ULL * 320 * 2);
  _Float16* W_cat_h = (_Float16*)alloc(512ULL * 1024 * 2);
  _Float16* W_log_h = (_Float16*)alloc(45056ULL * 512 * 2);
  _Float16* A_log_h = (_Float16*)alloc(1024ULL * 512 * 2);
  _Float16* HCzT    = (_Float16*)alloc(33ULL * 32768 * 2);
  _Float16* HC_A    = (_Float16*)alloc(1024ULL * 1024 * 2);
  _Float16* Wz      = (_Float16*)alloc(2048ULL * 1024 * 2); // [Whh | M1]
  float* P        = (float*)alloc(1024ULL * 2048 * 4);
  float* bias_sum = (float*)alloc(2048ULL * 4);
  unsigned* bar   = (unsigned*)alloc(4096);
  unsigned* ES    = (unsigned*)alloc(32ULL * 400 * 4);   // energy exchange slab

  auto blocks = [](long total) { return (int)((total + 255) / 256); };

  // init + casts
  init_kernel<<<blocks(327680), 256, 0, stream>>>(inits, b_ih, b_hh, HCzT, bias_sum, X1_h, bar);
  cast_pad_kernel<<<blocks(12800L*512), 256, 0, stream>>>(enc,   enc_h,   12800, 512, 512, 512, 512, 12800L*512);
  cast_pad_kernel<<<blocks(512L*512),   256, 0, stream>>>(W_enc, W_enc_h, 512,   512, 512, 512, 512, 512L*512);
  cast_pad_kernel<<<blocks(384L*320),   256, 0, stream>>>(W_red, Wr1_h,   300,   300, 812, 320, 320, 384L*320);
  cast_pad_kernel<<<blocks(2048L*320),  256, 0, stream>>>(W_ih,  W_ih_h,  2048,  300, 300, 320, 320, 2048L*320);
  cast_pad_kernel<<<blocks(512L*1024),  256, 0, stream>>>(W_cat, W_cat_h, 512,  1024, 1024, 1024, 1024, 512L*1024);
  cast_pad_kernel<<<blocks(45056L*512), 256, 0, stream>>>(W_log, W_log_h, 45000, 512, 512, 512, 512, 45056L*512);
  cast_pad_kernel<<<blocks(2048L*512),  256, 0, stream>>>(W_hh,  Wz,      2048,  512, 512, 512, 1024, 2048L*512);
  cast_emb_kernel<<<blocks(1024L*320), 256, 0, stream>>>(trg, emb_h);
  cast_wr2t_kernel<<<blocks(512L*320), 256, 0, stream>>>(W_red, Wr2T_h);

  // batched pre-GEMMs (grid = ntm*ntn, last arg = ntn)
  gemm_f16<1><<<400, 256, 0, stream>>>(enc_h, W_enc_h, nullptr, mem_h, b_enc, 512, 512, 512, 4);
  gemm_f16<1><<<24,  256, 0, stream>>>(emb_h, Wr1_h, nullptr, X1_h, b_red, 300, 320, 320, 3);
  gemm_f16<0><<<128, 256, 0, stream>>>(X1_h, W_ih_h, P, nullptr, bias_sum, 2048, 320, 2048, 16);
  gemm_f16<1><<<64,  256, 0, stream>>>(W_ih_h, Wr2T_h, nullptr, Wz + 512, nullptr, 512, 320, 1024, 4);

  // fused persistent recurrence (64 blocks, pair per batch, 3 barriers/step)
  fused_loop<<<64, 512, 0, stream>>>(mem_h, HCzT, HC_A, Wz, P, inits, mask,
                                     out_energy, out_attn, out_cov, bar, ES);

  // epilogue
  gemm_f16<2><<<32, 256, 0, stream>>>(HC_A, W_cat_h, nullptr, A_log_h, b_cat, 512, 1024, 512, 4);
  gemm_f16<3><<<2816, 256, 0, stream>>>(A_log_h, W_log_h, out_logits, nullptr, b_log, 45000, 512, 45050, 352);
  pointer_kernel<<<1024, 512, 0, stream>>>(ext, out_energy, out_logits);
}

// Round 16
// 1212.153 us; speedup vs baseline: 1.3463x; 1.3463x over previous
//
#include <hip/hip_runtime.h>
#include <hip/hip_bf16.h>

typedef _Float16 h2 __attribute__((ext_vector_type(2)));
typedef _Float16 h8 __attribute__((ext_vector_type(8)));
typedef __attribute__((ext_vector_type(4))) float floatx4;
typedef __attribute__((ext_vector_type(2))) float f32x2;

#define NEGF 1.0e12f

#if __has_builtin(__builtin_amdgcn_fdot2)
#define DOT2(a,b,c) __builtin_amdgcn_fdot2((a),(b),(c),false)
#else
static __device__ __forceinline__ float DOT2(h2 a, h2 b, float c){
  return c + (float)a[0]*(float)b[0] + (float)a[1]*(float)b[1];
}
#endif

__device__ __forceinline__ float dot8(h8 a, h8 b, float c){
  h2 a0 = {a[0],a[1]}, a1 = {a[2],a[3]}, a2 = {a[4],a[5]}, a3 = {a[6],a[7]};
  h2 b0 = {b[0],b[1]}, b1 = {b[2],b[3]}, b2 = {b[4],b[5]}, b3 = {b[6],b[7]};
  c = DOT2(a0,b0,c); c = DOT2(a1,b1,c); c = DOT2(a2,b2,c); c = DOT2(a3,b3,c);
  return c;
}

__device__ __forceinline__ unsigned f16bits(float x){
  union { _Float16 h; unsigned short u; } cv; cv.h = (_Float16)x; return (unsigned)cv.u;
}

#define GLD_LDS16(g, l) __builtin_amdgcn_global_load_lds( \
    (const __attribute__((address_space(1))) void*)(g),   \
    (__attribute__((address_space(3))) void*)(l), 16, 0, 0)

#define ALOAD64(p)    __hip_atomic_load((p), __ATOMIC_RELAXED, __HIP_MEMORY_SCOPE_AGENT)
#define ALOAD32(p)    __hip_atomic_load((p), __ATOMIC_RELAXED, __HIP_MEMORY_SCOPE_AGENT)
#define ASTORE32(p,v) __hip_atomic_store((p), (v), __ATOMIC_RELAXED, __HIP_MEMORY_SCOPE_AGENT)

// ---------------- generic f16 MFMA GEMM: C[M,N] = A[M,K] @ B[N,K]^T ----------------
// EPI3: bm = bid & 7, bn = bid >> 3 (8 row-tiles of one B-tile adjacent in dispatch
// order -> W_log HBM-read ~once); logits written with non-temporal stores (no RFO).
template<int EPI>
__global__ __launch_bounds__(256) void gemm_f16(
    const _Float16* __restrict__ A, const _Float16* __restrict__ B,
    float* __restrict__ Cf, _Float16* __restrict__ Ch,
    const float* __restrict__ bias, int N, int K, int ldc, int ntn)
{
  __shared__ char smem[32768];
  _Float16* Al = (_Float16*)smem;
  _Float16* Bl = (_Float16*)(smem + 16384);
  int bid = blockIdx.x;
  int bn, bm;
  if (EPI == 3) { bm = bid & 7; bn = bid >> 3; }
  else          { bn = bid % ntn; bm = bid / ntn; }
  int t = threadIdx.x;
  int w = t >> 6, l = t & 63;

  floatx4 acc[4][4];
#pragma unroll
  for (int i = 0; i < 4; ++i)
#pragma unroll
    for (int j = 0; j < 4; ++j) acc[i][j] = (floatx4){0.f, 0.f, 0.f, 0.f};

  const char* Ab = (const char*)A + (size_t)bm * 128 * K * 2;
  const char* Bb = (const char*)B + (size_t)bn * 128 * K * 2;
  const int rowb = K * 2;
  const int r0 = t >> 3;
  const int cbyte = ((t & 7) * 16) ^ (((t >> 3) & 7) << 4);
  char* AlB = (char*)Al;
  char* BlB = (char*)Bl;
  const int wm = (w >> 1) * 64, wn = (w & 1) * 64;

  for (int kt = 0; kt < K; kt += 64) {
    __syncthreads();
#pragma unroll
    for (int c = 0; c < 4; ++c) {
      int row = c * 32 + r0;
      GLD_LDS16(Ab + (size_t)row * rowb + kt * 2 + cbyte, AlB + c * 4096 + t * 16);
      GLD_LDS16(Bb + (size_t)row * rowb + kt * 2 + cbyte, BlB + c * 4096 + t * 16);
    }
    __syncthreads();
#pragma unroll
    for (int kk = 0; kk < 64; kk += 32) {
      h8 af[4], bfv[4];
#pragma unroll
      for (int i = 0; i < 4; ++i) {
        int ra = wm + i * 16 + (l & 15);
        int cb = ((kk << 1) + ((l >> 4) << 4)) ^ ((ra & 7) << 4);
        af[i] = *(const h8*)(AlB + ra * 128 + cb);
      }
#pragma unroll
      for (int j = 0; j < 4; ++j) {
        int ra = wn + j * 16 + (l & 15);
        int cb = ((kk << 1) + ((l >> 4) << 4)) ^ ((ra & 7) << 4);
        bfv[j] = *(const h8*)(BlB + ra * 128 + cb);
      }
#pragma unroll
      for (int i = 0; i < 4; ++i)
#pragma unroll
        for (int j = 0; j < 4; ++j)
          acc[i][j] = __builtin_amdgcn_mfma_f32_16x16x32_f16(af[i], bfv[j], acc[i][j], 0, 0, 0);
    }
  }

  if (EPI == 3) {
    float* Cs = (float*)smem;
#pragma unroll
    for (int half = 0; half < 2; ++half) {
      __syncthreads();
      if ((w >> 1) == half) {
        int rbase = ((l >> 4) << 2);
#pragma unroll
        for (int i = 0; i < 4; ++i)
#pragma unroll
          for (int j = 0; j < 4; ++j)
#pragma unroll
            for (int r = 0; r < 4; ++r)
              Cs[(i * 16 + rbase + r) * 128 + wn + j * 16 + (l & 15)] = acc[i][j][r];
      }
      __syncthreads();
#pragma unroll
      for (int rr = 0; rr < 16; ++rr) {
        int row = rr * 4 + w;
        int grow = bm * 128 + half * 64 + row;
        int cc = bn * 128 + 2 * l;
        float2 v = *(float2*)&Cs[row * 128 + 2 * l];
        float vv0, vv1;
        if (cc < N)     { float x0 = v.x + bias[cc];     vv0 = (x0 == 0.f) ? -NEGF : x0; } else vv0 = -NEGF;
        if (cc + 1 < N) { float x1 = v.y + bias[cc + 1]; vv1 = (x1 == 0.f) ? -NEGF : x1; } else vv1 = -NEGF;
        float* orow = Cf + (size_t)grow * ldc;
        if (cc + 1 < ldc) {
          f32x2 o; o.x = vv0; o.y = vv1;
          __builtin_nontemporal_store(o, (f32x2*)(orow + cc));
        } else if (cc < ldc) {
          __builtin_nontemporal_store(vv0, orow + cc);
        }
      }
    }
  } else {
    int mbase = bm * 128 + wm + ((l >> 4) << 2);
    int nbase = bn * 128 + wn + (l & 15);
#pragma unroll
    for (int j = 0; j < 4; ++j) {
      int col = nbase + j * 16;
#pragma unroll
      for (int i = 0; i < 4; ++i) {
#pragma unroll
        for (int r = 0; r < 4; ++r) {
          int row = mbase + i * 16 + r;
          float v = acc[i][j][r];
          if (col < N) {
            float bv = bias ? bias[col] : 0.f;
            if (EPI == 0)      Cf[(size_t)row * ldc + col] = v + bv;
            else if (EPI == 1) Ch[(size_t)row * ldc + col] = (_Float16)(v + bv);
            else               Ch[(size_t)row * ldc + col] = (_Float16)tanhf(v + bv);
          }
        }
      }
    }
  }
}

// ---------------- cast / pad kernels ----------------
__global__ void cast_pad_kernel(const float* __restrict__ src, _Float16* __restrict__ dst,
                                int R, int C, int ld_src, int Cpad, int ld_dst, long total){
  long i = (long)blockIdx.x * 256 + threadIdx.x;
  if (i >= total) return;
  int r = (int)(i / Cpad), c = (int)(i % Cpad);
  float v = (r < R && c < C) ? src[(size_t)r * ld_src + c] : 0.f;
  dst[(size_t)r * ld_dst + c] = (_Float16)v;
}

__global__ void cast_emb_kernel(const float* __restrict__ trg, _Float16* __restrict__ dst){
  int i = blockIdx.x * 256 + threadIdx.x;
  if (i >= 1024 * 320) return;
  int m = i / 320, e = i % 320;
  int tt = m >> 5, b = m & 31;
  float v = (e < 300) ? trg[((size_t)b * 32 + tt) * 300 + e] : 0.f;
  dst[i] = (_Float16)v;
}

__global__ void cast_wr2t_kernel(const float* __restrict__ wred, _Float16* __restrict__ dst){
  int i = blockIdx.x * 256 + threadIdx.x;
  if (i >= 512 * 320) return;
  int h = i / 320, e = i % 320;
  float v = (e < 300) ? wred[(size_t)e * 812 + 300 + h] : 0.f;
  dst[i] = (_Float16)v;
}

// HCzT slab: unit u = kc*32 + b (16B each), holds z[b][kc*8 .. kc*8+8]
__global__ void init_kernel(const float* __restrict__ h0, const float* __restrict__ b_ih,
                            const float* __restrict__ b_hh,
                            _Float16* __restrict__ HCzT, float* __restrict__ bias_sum,
                            _Float16* __restrict__ X1h, unsigned* __restrict__ bar){
  int i = blockIdx.x * 256 + threadIdx.x;
  if (i < 32768) {
    int unit = i >> 3, pos = i & 7;
    int kc = unit >> 5, b = unit & 31;
    int k = kc * 8 + pos;
    HCzT[i] = (k < 512) ? (_Float16)h0[b * 512 + k] : (_Float16)0.f;
  }
  if (i < 2048)  bias_sum[i] = b_ih[i] + b_hh[i];
  if (i < 327680) X1h[i] = (_Float16)0.f;
  if (i < 1024) bar[i] = 0u;
}

// ---------------- fence-free flag barrier (R12-proven) ----------------
__device__ __forceinline__ void gbar(unsigned* flags, unsigned gen){
  asm volatile("s_waitcnt vmcnt(0)" ::: "memory");   // drain this wave's bypass stores
  __syncthreads();
  if (threadIdx.x == 0) {
    ASTORE32(flags + blockIdx.x, gen);               // independent arrival store (no RMW)
    for (;;) {
      bool done = true;
#pragma unroll
      for (int i = 0; i < 32; ++i)
        done &= (ALOAD32(flags + i) >= gen);
      if (done) break;
      __builtin_amdgcn_s_sleep(2);
    }
  }
  __syncthreads();
  asm volatile("" ::: "memory");
}

// ---------------- fused persistent recurrence: 32 blocks x 512 threads (R12) ----------------
__global__ __launch_bounds__(512, 1) void fused_loop(
    const _Float16* __restrict__ memh, _Float16* __restrict__ HCzT,
    _Float16* __restrict__ HC_A, const _Float16* __restrict__ Wz,
    const float* __restrict__ P, const float* __restrict__ inits,
    const int* __restrict__ mask, float* __restrict__ e_out,
    float* __restrict__ a_out, float* __restrict__ c_out, unsigned* __restrict__ bar)
{
  __shared__ char smem[32768];      // phase A: gl[8192] floats
  __shared__ __align__(16) float es[400];
  __shared__ float red[16];
  __shared__ float cum[400];
  __shared__ _Float16 hh[512];

  float* gl = (float*)smem;
  const int q = blockIdx.x, t = threadIdx.x;
  const int w = t >> 6, l = t & 63;
  const int mw = w >> 2, nw = w & 3;    // batch-half, k-quarter

  if (t < 400) cum[t] = 0.f;

  float creg = inits[(t >> 4) * 512 + q * 16 + (t & 15)];   // c0 = h0
  const _Float16* mb = memh + (size_t)q * 400 * 512;

  // per-gate weight row base (L2-resident)
  const _Float16* wbase[4];
#pragma unroll
  for (int s = 0; s < 4; ++s)
    wbase[s] = Wz + (size_t)(s * 512 + q * 16 + (l & 15)) * 1024 + nw * 256 + ((l >> 4) << 3);

  __syncthreads();

  for (int ts = 0; ts < 32; ++ts) {
    // ======== phase A: gates MFMA ========
    {
      unsigned long long* zsrc = (unsigned long long*)(HCzT + (size_t)ts * 32768);
      floatx4 acc[4];
#pragma unroll
      for (int s = 0; s < 4; ++s) acc[s] = (floatx4){0.f, 0.f, 0.f, 0.f};
#pragma unroll
      for (int kk8 = 0; kk8 < 8; ++kk8) {
        int unit = ((nw * 8 + kk8) * 4 + (l >> 4)) * 32 + mw * 16 + (l & 15);
        union { unsigned long long u[2]; h8 v; } za;
        za.u[0] = ALOAD64(zsrc + (size_t)unit * 2);
        za.u[1] = ALOAD64(zsrc + (size_t)unit * 2 + 1);
#pragma unroll
        for (int s = 0; s < 4; ++s) {
          h8 wv = *(const h8*)(wbase[s] + kk8 * 32);
          acc[s] = __builtin_amdgcn_mfma_f32_16x16x32_f16(za.v, wv, acc[s], 0, 0, 0);
        }
      }
#pragma unroll
      for (int s = 0; s < 4; ++s)
#pragma unroll
        for (int r = 0; r < 4; ++r) {
          int b = mw * 16 + ((l >> 4) << 2) + r;
          gl[(s * 4 + nw) * 512 + b * 16 + (l & 15)] = acc[s][r];
        }
    }
    __syncthreads();
    // ---- LSTM pointwise: thread t -> (b = t>>4, j16 = t&15) ----
    {
      int b = t >> 4, j16 = t & 15;
      const float* Pr = P + ((size_t)ts * 32 + b) * 2048 + q * 16 + j16;
      float g4[4];
#pragma unroll
      for (int s = 0; s < 4; ++s)
        g4[s] = gl[(s * 4 + 0) * 512 + t] + gl[(s * 4 + 1) * 512 + t]
              + gl[(s * 4 + 2) * 512 + t] + gl[(s * 4 + 3) * 512 + t] + Pr[s * 512];
      float ig = 1.f / (1.f + expf(-g4[0]));
      float fg = 1.f / (1.f + expf(-g4[1]));
      float og = 1.f / (1.f + expf(-g4[3]));
      float cn = fg * creg + ig * tanhf(g4[2]);
      float hn = og * tanhf(cn);
      creg = cn;
      unsigned hu = f16bits(hn);
      unsigned other = __shfl_xor(hu, 1);
      if (!(t & 1)) {
        unsigned pack = hu | (other << 16);
        int j = q * 16 + j16;
        unsigned* dst = (unsigned*)((char*)(HCzT + (size_t)(ts + 1) * 32768)
                                    + (((j >> 3) * 32 + b) << 4) + ((j & 7) << 1));
        ASTORE32(dst, pack);
        *(unsigned*)(HC_A + ((size_t)ts * 32 + b) * 1024 + j) = pack;
      }
    }
    gbar(bar, 2 * ts + 1);

    // ======== phase B: attention for batch q ========
    size_t obase = (size_t)ts * 12800 + q * 400;
    {
      // h -> LDS
      if (t < 64) {
        unsigned long long* hsrc = (unsigned long long*)(HCzT + (size_t)(ts + 1) * 32768);
        union { unsigned long long u[2]; h8 v; } ha;
        ha.u[0] = ALOAD64(hsrc + ((size_t)t * 32 + q) * 2);
        ha.u[1] = ALOAD64(hsrc + ((size_t)t * 32 + q) * 2 + 1);
        *(h8*)&hh[t * 8] = ha.v;
      }
      __syncthreads();

      // energy: 4 lanes per s-row (d-chunks of 128), 2-level shuffle reduce
      {
        int g = l >> 2, c = l & 3;
#pragma unroll
        for (int r = 0; r < 4; ++r) {
          int sr = r * 16 + g;
          if (sr < 50) {
            int s = w * 50 + sr;
            const _Float16* row = mb + (size_t)s * 512 + c * 128;
            float e = 0.f;
#pragma unroll
            for (int k = 0; k < 16; ++k)
              e = dot8(*(const h8*)(row + k * 8), *(const h8*)&hh[c * 128 + k * 8], e);
            e += __shfl_xor(e, 1);
            e += __shfl_xor(e, 2);
            if (c == 0) {
              if (mask[q * 400 + s] == 0) e = -NEGF;
              es[s] = e;
            }
          }
        }
      }
      __syncthreads();
      if (t < 400) e_out[obase + t] = es[t];

      // softmax over es[400]
      float v = (t < 400) ? es[t] : -3.4e38f;
      float m = v;
#pragma unroll
      for (int o = 32; o; o >>= 1) m = fmaxf(m, __shfl_xor(m, o));
      if (l == 0) red[w] = m;
      __syncthreads();
      m = red[0];
#pragma unroll
      for (int qq = 1; qq < 8; ++qq) m = fmaxf(m, red[qq]);
      float p = (t < 400) ? expf(v - m) : 0.f;
      float sum = p;
#pragma unroll
      for (int o = 32; o; o >>= 1) sum += __shfl_xor(sum, o);
      if (l == 0) red[8 + w] = sum;
      __syncthreads();
      float tot = red[8];
#pragma unroll
      for (int qq = 9; qq < 16; ++qq) tot += red[qq];
      float inv = 1.f / tot;
      float aval = p * inv;
      if (t < 400) {
        es[t] = aval;                       // normalized attn for ctx pass
        a_out[obase + t] = aval;
        c_out[obase + t] = cum[t];          // coverage (pre-update)
        cum[t] += aval;
      }
      __syncthreads();

      // context: thread t owns dim t; 4 independent accumulators, 16 loads in flight
      float a0 = 0.f, a1 = 0.f, a2 = 0.f, a3 = 0.f;
#pragma unroll 4
      for (int si = 0; si < 400; si += 4) {
        a0 += es[si + 0] * (float)mb[(size_t)(si + 0) * 512 + t];
        a1 += es[si + 1] * (float)mb[(size_t)(si + 1) * 512 + t];
        a2 += es[si + 2] * (float)mb[(size_t)(si + 2) * 512 + t];
        a3 += es[si + 3] * (float)mb[(size_t)(si + 3) * 512 + t];
      }
      float acc2 = (a0 + a1) + (a2 + a3);
      unsigned cu = f16bits(acc2);
      unsigned other = __shfl_xor(cu, 1);
      if (!(t & 1)) {
        unsigned pack = cu | (other << 16);
        int kg = 512 + t;
        unsigned* dst = (unsigned*)((char*)(HCzT + (size_t)(ts + 1) * 32768)
                                    + (((kg >> 3) * 32 + q) << 4) + ((kg & 7) << 1));
        ASTORE32(dst, pack);
        *(unsigned*)(HC_A + ((size_t)ts * 32 + q) * 1024 + kg) = pack;
      }
    }
    gbar(bar, 2 * ts + 2);
  }
}

// ---------------- pointer scatter-max patch ----------------
__global__ __launch_bounds__(512) void pointer_kernel(
    const int* __restrict__ ext, const float* __restrict__ energ, float* __restrict__ logits)
{
  __shared__ int ids[400];
  __shared__ float es[400];
  int tb = blockIdx.x;
  int b = tb & 31;
  int tt = tb >> 5;
  int t = threadIdx.x;
  if (t < 400) {
    ids[t] = ext[b * 400 + t];
    es[t] = energ[(size_t)tt * 12800 + b * 400 + t];
  }
  __syncthreads();
  if (t < 400) {
    int id = ids[t];
    bool first = true;
    for (int s = 0; s < t; ++s) if (ids[s] == id) { first = false; break; }
    if (first) {
      float mx = es[t];
      for (int s = t + 1; s < 400; ++s) if (ids[s] == id) mx = fmaxf(mx, es[s]);
      if (mx != -NEGF) {
        float* p = &logits[(size_t)tb * 45050 + id];
        float base = 0.f;
        if (id < 45000) { float cur = *p; base = (cur == -NEGF) ? 0.f : cur; }
        float nv = base + mx;
        *p = (nv == 0.f) ? -NEGF : nv;
      }
    }
  }
}

// ---------------- host launcher ----------------
extern "C" void kernel_launch(void* const* d_in, const int* in_sizes, int n_in,
                              void* d_out, int out_size, void* d_ws, size_t ws_size,
                              hipStream_t stream) {
  const float* trg   = (const float*)d_in[0];
  const int*   ext   = (const int*)d_in[1];
  const float* inits = (const float*)d_in[2];
  const float* enc   = (const float*)d_in[3];
  const int*   mask  = (const int*)d_in[4];
  const float* W_enc = (const float*)d_in[5];
  const float* b_enc = (const float*)d_in[6];
  const float* W_red = (const float*)d_in[7];
  const float* b_red = (const float*)d_in[8];
  const float* W_ih  = (const float*)d_in[9];
  const float* W_hh  = (const float*)d_in[10];
  const float* b_ih  = (const float*)d_in[11];
  const float* b_hh  = (const float*)d_in[12];
  const float* W_cat = (const float*)d_in[13];
  const float* b_cat = (const float*)d_in[14];
  const float* W_log = (const float*)d_in[15];
  const float* b_log = (const float*)d_in[16];

  float* out = (float*)d_out;
  float* out_logits = out;                       // [1024 x 45050]
  float* out_attn   = out + 46131200;
  float* out_cov    = out_attn + 409600;
  float* out_energy = out_cov + 409600;

  char* ws = (char*)d_ws;
  size_t o = 0;
  auto alloc = [&](size_t bytes) { void* p = ws + o; o += (bytes + 255) & ~(size_t)255; return p; };
  _Float16* mem_h   = (_Float16*)alloc(12800ULL * 512 * 2);
  _Float16* enc_h   = (_Float16*)alloc(12800ULL * 512 * 2);
  _Float16* W_enc_h = (_Float16*)alloc(512ULL * 512 * 2);
  _Float16* emb_h   = (_Float16*)alloc(1024ULL * 320 * 2);
  _Float16* Wr1_h   = (_Float16*)alloc(384ULL * 320 * 2);
  _Float16* X1_h    = (_Float16*)alloc(1024ULL * 320 * 2);
  _Float16* W_ih_h  = (_Float16*)alloc(2048ULL * 320 * 2);
  _Float16* Wr2T_h  = (_Float16*)alloc(512ULL * 320 * 2);
  _Float16* W_cat_h = (_Float16*)alloc(512ULL * 1024 * 2);
  _Float16* W_log_h = (_Float16*)alloc(45056ULL * 512 * 2);
  _Float16* A_log_h = (_Float16*)alloc(1024ULL * 512 * 2);
  _Float16* HCzT    = (_Float16*)alloc(33ULL * 32768 * 2);
  _Float16* HC_A    = (_Float16*)alloc(1024ULL * 1024 * 2);
  _Float16* Wz      = (_Float16*)alloc(2048ULL * 1024 * 2); // [Whh | M1]
  float* P        = (float*)alloc(1024ULL * 2048 * 4);
  float* bias_sum = (float*)alloc(2048ULL * 4);
  unsigned* bar   = (unsigned*)alloc(4096);

  auto blocks = [](long total) { return (int)((total + 255) / 256); };

  // init + casts
  init_kernel<<<blocks(327680), 256, 0, stream>>>(inits, b_ih, b_hh, HCzT, bias_sum, X1_h, bar);
  cast_pad_kernel<<<blocks(12800L*512), 256, 0, stream>>>(enc,   enc_h,   12800, 512, 512, 512, 512, 12800L*512);
  cast_pad_kernel<<<blocks(512L*512),   256, 0, stream>>>(W_enc, W_enc_h, 512,   512, 512, 512, 512, 512L*512);
  cast_pad_kernel<<<blocks(384L*320),   256, 0, stream>>>(W_red, Wr1_h,   300,   300, 812, 320, 320, 384L*320);
  cast_pad_kernel<<<blocks(2048L*320),  256, 0, stream>>>(W_ih,  W_ih_h,  2048,  300, 300, 320, 320, 2048L*320);
  cast_pad_kernel<<<blocks(512L*1024),  256, 0, stream>>>(W_cat, W_cat_h, 512,  1024, 1024, 1024, 1024, 512L*1024);
  cast_pad_kernel<<<blocks(45056L*512), 256, 0, stream>>>(W_log, W_log_h, 45000, 512, 512, 512, 512, 45056L*512);
  cast_pad_kernel<<<blocks(2048L*512),  256, 0, stream>>>(W_hh,  Wz,      2048,  512, 512, 512, 1024, 2048L*512);
  cast_emb_kernel<<<blocks(1024L*320), 256, 0, stream>>>(trg, emb_h);
  cast_wr2t_kernel<<<blocks(512L*320), 256, 0, stream>>>(W_red, Wr2T_h);

  // batched pre-GEMMs (grid = ntm*ntn, last arg = ntn)
  gemm_f16<1><<<400, 256, 0, stream>>>(enc_h, W_enc_h, nullptr, mem_h, b_enc, 512, 512, 512, 4);
  gemm_f16<1><<<24,  256, 0, stream>>>(emb_h, Wr1_h, nullptr, X1_h, b_red, 300, 320, 320, 3);
  gemm_f16<0><<<128, 256, 0, stream>>>(X1_h, W_ih_h, P, nullptr, bias_sum, 2048, 320, 2048, 16);
  gemm_f16<1><<<64,  256, 0, stream>>>(W_ih_h, Wr2T_h, nullptr, Wz + 512, nullptr, 512, 320, 1024, 4);

  // fused persistent recurrence (R12-proven)
  fused_loop<<<32, 512, 0, stream>>>(mem_h, HCzT, HC_A, Wz, P, inits, mask,
                                     out_energy, out_attn, out_cov, bar);

  // epilogue
  gemm_f16<2><<<32, 256, 0, stream>>>(HC_A, W_cat_h, nullptr, A_log_h, b_cat, 512, 1024, 512, 4);
  gemm_f16<3><<<2816, 256, 0, stream>>>(A_log_h, W_log_h, out_logits, nullptr, b_log, 45000, 512, 45050, 352);
  pointer_kernel<<<1024, 512, 0, stream>>>(ext, out_energy, out_logits);
}

// Round 17
// 1186.102 us; speedup vs baseline: 1.3759x; 1.0220x over previous
//
#include <hip/hip_runtime.h>
#include <hip/hip_bf16.h>

typedef _Float16 h2 __attribute__((ext_vector_type(2)));
typedef _Float16 h8 __attribute__((ext_vector_type(8)));
typedef __attribute__((ext_vector_type(4))) float floatx4;
typedef __attribute__((ext_vector_type(2))) float f32x2;

#define NEGF 1.0e12f

#if __has_builtin(__builtin_amdgcn_fdot2)
#define DOT2(a,b,c) __builtin_amdgcn_fdot2((a),(b),(c),false)
#else
static __device__ __forceinline__ float DOT2(h2 a, h2 b, float c){
  return c + (float)a[0]*(float)b[0] + (float)a[1]*(float)b[1];
}
#endif

__device__ __forceinline__ float dot8(h8 a, h8 b, float c){
  h2 a0 = {a[0],a[1]}, a1 = {a[2],a[3]}, a2 = {a[4],a[5]}, a3 = {a[6],a[7]};
  h2 b0 = {b[0],b[1]}, b1 = {b[2],b[3]}, b2 = {b[4],b[5]}, b3 = {b[6],b[7]};
  c = DOT2(a0,b0,c); c = DOT2(a1,b1,c); c = DOT2(a2,b2,c); c = DOT2(a3,b3,c);
  return c;
}

__device__ __forceinline__ unsigned f16bits(float x){
  union { _Float16 h; unsigned short u; } cv; cv.h = (_Float16)x; return (unsigned)cv.u;
}

#define GLD_LDS16(g, l) __builtin_amdgcn_global_load_lds( \
    (const __attribute__((address_space(1))) void*)(g),   \
    (__attribute__((address_space(3))) void*)(l), 16, 0, 0)

#define ALOAD64(p)    __hip_atomic_load((p), __ATOMIC_RELAXED, __HIP_MEMORY_SCOPE_AGENT)
#define ALOAD32(p)    __hip_atomic_load((p), __ATOMIC_RELAXED, __HIP_MEMORY_SCOPE_AGENT)
#define ASTORE32(p,v) __hip_atomic_store((p), (v), __ATOMIC_RELAXED, __HIP_MEMORY_SCOPE_AGENT)

// ---------------- generic f16 MFMA GEMM: C[M,N] = A[M,K] @ B[N,K]^T ----------------
template<int EPI>
__global__ __launch_bounds__(256) void gemm_f16(
    const _Float16* __restrict__ A, const _Float16* __restrict__ B,
    float* __restrict__ Cf, _Float16* __restrict__ Ch,
    const float* __restrict__ bias, int N, int K, int ldc, int ntn)
{
  __shared__ char smem[32768];
  _Float16* Al = (_Float16*)smem;
  _Float16* Bl = (_Float16*)(smem + 16384);
  int bid = blockIdx.x;
  int bn, bm;
  if (EPI == 3) { bm = bid & 7; bn = bid >> 3; }
  else          { bn = bid % ntn; bm = bid / ntn; }
  int t = threadIdx.x;
  int w = t >> 6, l = t & 63;

  floatx4 acc[4][4];
#pragma unroll
  for (int i = 0; i < 4; ++i)
#pragma unroll
    for (int j = 0; j < 4; ++j) acc[i][j] = (floatx4){0.f, 0.f, 0.f, 0.f};

  const char* Ab = (const char*)A + (size_t)bm * 128 * K * 2;
  const char* Bb = (const char*)B + (size_t)bn * 128 * K * 2;
  const int rowb = K * 2;
  const int r0 = t >> 3;
  const int cbyte = ((t & 7) * 16) ^ (((t >> 3) & 7) << 4);
  char* AlB = (char*)Al;
  char* BlB = (char*)Bl;
  const int wm = (w >> 1) * 64, wn = (w & 1) * 64;

  for (int kt = 0; kt < K; kt += 64) {
    __syncthreads();
#pragma unroll
    for (int c = 0; c < 4; ++c) {
      int row = c * 32 + r0;
      GLD_LDS16(Ab + (size_t)row * rowb + kt * 2 + cbyte, AlB + c * 4096 + t * 16);
      GLD_LDS16(Bb + (size_t)row * rowb + kt * 2 + cbyte, BlB + c * 4096 + t * 16);
    }
    __syncthreads();
#pragma unroll
    for (int kk = 0; kk < 64; kk += 32) {
      h8 af[4], bfv[4];
#pragma unroll
      for (int i = 0; i < 4; ++i) {
        int ra = wm + i * 16 + (l & 15);
        int cb = ((kk << 1) + ((l >> 4) << 4)) ^ ((ra & 7) << 4);
        af[i] = *(const h8*)(AlB + ra * 128 + cb);
      }
#pragma unroll
      for (int j = 0; j < 4; ++j) {
        int ra = wn + j * 16 + (l & 15);
        int cb = ((kk << 1) + ((l >> 4) << 4)) ^ ((ra & 7) << 4);
        bfv[j] = *(const h8*)(BlB + ra * 128 + cb);
      }
#pragma unroll
      for (int i = 0; i < 4; ++i)
#pragma unroll
        for (int j = 0; j < 4; ++j)
          acc[i][j] = __builtin_amdgcn_mfma_f32_16x16x32_f16(af[i], bfv[j], acc[i][j], 0, 0, 0);
    }
  }

  if (EPI == 3) {
    float* Cs = (float*)smem;
#pragma unroll
    for (int half = 0; half < 2; ++half) {
      __syncthreads();
      if ((w >> 1) == half) {
        int rbase = ((l >> 4) << 2);
#pragma unroll
        for (int i = 0; i < 4; ++i)
#pragma unroll
          for (int j = 0; j < 4; ++j)
#pragma unroll
            for (int r = 0; r < 4; ++r)
              Cs[(i * 16 + rbase + r) * 128 + wn + j * 16 + (l & 15)] = acc[i][j][r];
      }
      __syncthreads();
#pragma unroll
      for (int rr = 0; rr < 16; ++rr) {
        int row = rr * 4 + w;
        int grow = bm * 128 + half * 64 + row;
        int cc = bn * 128 + 2 * l;
        float2 v = *(float2*)&Cs[row * 128 + 2 * l];
        float vv0, vv1;
        if (cc < N)     { float x0 = v.x + bias[cc];     vv0 = (x0 == 0.f) ? -NEGF : x0; } else vv0 = -NEGF;
        if (cc + 1 < N) { float x1 = v.y + bias[cc + 1]; vv1 = (x1 == 0.f) ? -NEGF : x1; } else vv1 = -NEGF;
        float* orow = Cf + (size_t)grow * ldc;
        if (cc + 1 < ldc) {
          f32x2 o; o.x = vv0; o.y = vv1;
          __builtin_nontemporal_store(o, (f32x2*)(orow + cc));
        } else if (cc < ldc) {
          __builtin_nontemporal_store(vv0, orow + cc);
        }
      }
    }
  } else {
    int mbase = bm * 128 + wm + ((l >> 4) << 2);
    int nbase = bn * 128 + wn + (l & 15);
#pragma unroll
    for (int j = 0; j < 4; ++j) {
      int col = nbase + j * 16;
#pragma unroll
      for (int i = 0; i < 4; ++i) {
#pragma unroll
        for (int r = 0; r < 4; ++r) {
          int row = mbase + i * 16 + r;
          float v = acc[i][j][r];
          if (col < N) {
            float bv = bias ? bias[col] : 0.f;
            if (EPI == 0)      Cf[(size_t)row * ldc + col] = v + bv;
            else if (EPI == 1) Ch[(size_t)row * ldc + col] = (_Float16)(v + bv);
            else               Ch[(size_t)row * ldc + col] = (_Float16)tanhf(v + bv);
          }
        }
      }
    }
  }
}

// ---------------- consolidated prologue: init + all casts in ONE kernel ----------------
__device__ __forceinline__ void castseg(const float* __restrict__ src, _Float16* __restrict__ dst,
                                        int R, int C, int ld_src, int Cpad, int ld_dst, long i){
  int r = (int)(i / Cpad), c = (int)(i % Cpad);
  float v = (r < R && c < C) ? src[(size_t)r * ld_src + c] : 0.f;
  dst[(size_t)r * ld_dst + c] = (_Float16)v;
}

// segment block offsets (each segment total is a multiple of 256)
#define SB0 1280      // init       (327680)
#define SB1 26880     // enc        (+25600)
#define SB2 27904     // W_enc      (+1024)
#define SB3 28384     // Wr1        (+480)
#define SB4 30944     // W_ih       (+2560)
#define SB5 32992     // W_cat      (+2048)
#define SB6 123104    // W_log      (+90112)
#define SB7 127200    // W_hh->Wz   (+4096)
#define SB8 128480    // emb        (+1280)
#define SB9 129120    // wr2t       (+640)

__global__ __launch_bounds__(256) void prep_kernel(
    const float* __restrict__ h0, const float* __restrict__ b_ih, const float* __restrict__ b_hh,
    const float* __restrict__ enc, const float* __restrict__ W_enc, const float* __restrict__ W_red,
    const float* __restrict__ W_ih, const float* __restrict__ W_cat, const float* __restrict__ W_log,
    const float* __restrict__ W_hh, const float* __restrict__ trg,
    _Float16* __restrict__ HCzT, float* __restrict__ bias_sum, _Float16* __restrict__ X1h,
    unsigned* __restrict__ bar, _Float16* __restrict__ enc_h, _Float16* __restrict__ W_enc_h,
    _Float16* __restrict__ Wr1_h, _Float16* __restrict__ W_ih_h, _Float16* __restrict__ W_cat_h,
    _Float16* __restrict__ W_log_h, _Float16* __restrict__ Wz, _Float16* __restrict__ emb_h,
    _Float16* __restrict__ Wr2T_h)
{
  int bid = blockIdx.x, t = threadIdx.x;
  if (bid < SB0) {                                  // init (verbatim init_kernel body)
    long i = (long)bid * 256 + t;
    if (i < 32768) {
      int unit = (int)(i >> 3), pos = (int)(i & 7);
      int kc = unit >> 5, b = unit & 31;
      int k = kc * 8 + pos;
      HCzT[i] = (k < 512) ? (_Float16)h0[b * 512 + k] : (_Float16)0.f;
    }
    if (i < 2048)  bias_sum[i] = b_ih[i] + b_hh[i];
    if (i < 327680) X1h[i] = (_Float16)0.f;
    if (i < 1024) bar[i] = 0u;
  } else if (bid < SB1) {                           // enc cast
    long i = (long)(bid - SB0) * 256 + t;
    castseg(enc, enc_h, 12800, 512, 512, 512, 512, i);
  } else if (bid < SB2) {                           // W_enc
    long i = (long)(bid - SB1) * 256 + t;
    castseg(W_enc, W_enc_h, 512, 512, 512, 512, 512, i);
  } else if (bid < SB3) {                           // Wr1 (W_red[:,:300])
    long i = (long)(bid - SB2) * 256 + t;
    castseg(W_red, Wr1_h, 300, 300, 812, 320, 320, i);
  } else if (bid < SB4) {                           // W_ih
    long i = (long)(bid - SB3) * 256 + t;
    castseg(W_ih, W_ih_h, 2048, 300, 300, 320, 320, i);
  } else if (bid < SB5) {                           // W_cat
    long i = (long)(bid - SB4) * 256 + t;
    castseg(W_cat, W_cat_h, 512, 1024, 1024, 1024, 1024, i);
  } else if (bid < SB6) {                           // W_log
    long i = (long)(bid - SB5) * 256 + t;
    castseg(W_log, W_log_h, 45000, 512, 512, 512, 512, i);
  } else if (bid < SB7) {                           // W_hh -> Wz cols 0..511 (ld_dst 1024)
    long i = (long)(bid - SB6) * 256 + t;
    castseg(W_hh, Wz, 2048, 512, 512, 512, 1024, i);
  } else if (bid < SB8) {                           // emb (verbatim cast_emb body)
    int i = (bid - SB7) * 256 + t;
    int m = i / 320, e = i % 320;
    int tt = m >> 5, b = m & 31;
    float v = (e < 300) ? trg[((size_t)b * 32 + tt) * 300 + e] : 0.f;
    emb_h[i] = (_Float16)v;
  } else if (bid < SB9) {                           // wr2t (verbatim cast_wr2t body)
    int i = (bid - SB8) * 256 + t;
    int h = i / 320, e = i % 320;
    float v = (e < 300) ? W_red[(size_t)e * 812 + 300 + h] : 0.f;
    Wr2T_h[i] = (_Float16)v;
  }
}

// ---------------- fence-free flag barrier (R12-proven) ----------------
__device__ __forceinline__ void gbar(unsigned* flags, unsigned gen){
  asm volatile("s_waitcnt vmcnt(0)" ::: "memory");   // drain this wave's bypass stores
  __syncthreads();
  if (threadIdx.x == 0) {
    ASTORE32(flags + blockIdx.x, gen);               // independent arrival store (no RMW)
    for (;;) {
      bool done = true;
#pragma unroll
      for (int i = 0; i < 32; ++i)
        done &= (ALOAD32(flags + i) >= gen);
      if (done) break;
      __builtin_amdgcn_s_sleep(2);
    }
  }
  __syncthreads();
  asm volatile("" ::: "memory");
}

// ---------------- fused persistent recurrence: 32 blocks x 512 threads (R12) ----------------
__global__ __launch_bounds__(512, 1) void fused_loop(
    const _Float16* __restrict__ memh, _Float16* __restrict__ HCzT,
    _Float16* __restrict__ HC_A, const _Float16* __restrict__ Wz,
    const float* __restrict__ P, const float* __restrict__ inits,
    const int* __restrict__ mask, float* __restrict__ e_out,
    float* __restrict__ a_out, float* __restrict__ c_out, unsigned* __restrict__ bar)
{
  __shared__ char smem[32768];      // phase A: gl[8192] floats
  __shared__ __align__(16) float es[400];
  __shared__ float red[16];
  __shared__ float cum[400];
  __shared__ _Float16 hh[512];

  float* gl = (float*)smem;
  const int q = blockIdx.x, t = threadIdx.x;
  const int w = t >> 6, l = t & 63;
  const int mw = w >> 2, nw = w & 3;    // batch-half, k-quarter

  if (t < 400) cum[t] = 0.f;

  float creg = inits[(t >> 4) * 512 + q * 16 + (t & 15)];   // c0 = h0
  const _Float16* mb = memh + (size_t)q * 400 * 512;

  // per-gate weight row base (L2-resident)
  const _Float16* wbase[4];
#pragma unroll
  for (int s = 0; s < 4; ++s)
    wbase[s] = Wz + (size_t)(s * 512 + q * 16 + (l & 15)) * 1024 + nw * 256 + ((l >> 4) << 3);

  __syncthreads();

  for (int ts = 0; ts < 32; ++ts) {
    // ======== phase A: gates MFMA ========
    {
      unsigned long long* zsrc = (unsigned long long*)(HCzT + (size_t)ts * 32768);
      floatx4 acc[4];
#pragma unroll
      for (int s = 0; s < 4; ++s) acc[s] = (floatx4){0.f, 0.f, 0.f, 0.f};
#pragma unroll
      for (int kk8 = 0; kk8 < 8; ++kk8) {
        int unit = ((nw * 8 + kk8) * 4 + (l >> 4)) * 32 + mw * 16 + (l & 15);
        union { unsigned long long u[2]; h8 v; } za;
        za.u[0] = ALOAD64(zsrc + (size_t)unit * 2);
        za.u[1] = ALOAD64(zsrc + (size_t)unit * 2 + 1);
#pragma unroll
        for (int s = 0; s < 4; ++s) {
          h8 wv = *(const h8*)(wbase[s] + kk8 * 32);
          acc[s] = __builtin_amdgcn_mfma_f32_16x16x32_f16(za.v, wv, acc[s], 0, 0, 0);
        }
      }
#pragma unroll
      for (int s = 0; s < 4; ++s)
#pragma unroll
        for (int r = 0; r < 4; ++r) {
          int b = mw * 16 + ((l >> 4) << 2) + r;
          gl[(s * 4 + nw) * 512 + b * 16 + (l & 15)] = acc[s][r];
        }
    }
    __syncthreads();
    // ---- LSTM pointwise: thread t -> (b = t>>4, j16 = t&15) ----
    {
      int b = t >> 4, j16 = t & 15;
      const float* Pr = P + ((size_t)ts * 32 + b) * 2048 + q * 16 + j16;
      float g4[4];
#pragma unroll
      for (int s = 0; s < 4; ++s)
        g4[s] = gl[(s * 4 + 0) * 512 + t] + gl[(s * 4 + 1) * 512 + t]
              + gl[(s * 4 + 2) * 512 + t] + gl[(s * 4 + 3) * 512 + t] + Pr[s * 512];
      float ig = 1.f / (1.f + expf(-g4[0]));
      float fg = 1.f / (1.f + expf(-g4[1]));
      float og = 1.f / (1.f + expf(-g4[3]));
      float cn = fg * creg + ig * tanhf(g4[2]);
      float hn = og * tanhf(cn);
      creg = cn;
      unsigned hu = f16bits(hn);
      unsigned other = __shfl_xor(hu, 1);
      if (!(t & 1)) {
        unsigned pack = hu | (other << 16);
        int j = q * 16 + j16;
        unsigned* dst = (unsigned*)((char*)(HCzT + (size_t)(ts + 1) * 32768)
                                    + (((j >> 3) * 32 + b) << 4) + ((j & 7) << 1));
        ASTORE32(dst, pack);
        *(unsigned*)(HC_A + ((size_t)ts * 32 + b) * 1024 + j) = pack;
      }
    }
    gbar(bar, 2 * ts + 1);

    // ======== phase B: attention for batch q ========
    size_t obase = (size_t)ts * 12800 + q * 400;
    {
      // h -> LDS
      if (t < 64) {
        unsigned long long* hsrc = (unsigned long long*)(HCzT + (size_t)(ts + 1) * 32768);
        union { unsigned long long u[2]; h8 v; } ha;
        ha.u[0] = ALOAD64(hsrc + ((size_t)t * 32 + q) * 2);
        ha.u[1] = ALOAD64(hsrc + ((size_t)t * 32 + q) * 2 + 1);
        *(h8*)&hh[t * 8] = ha.v;
      }
      __syncthreads();

      // energy: 4 lanes per s-row (d-chunks of 128), 2-level shuffle reduce
      {
        int g = l >> 2, c = l & 3;
#pragma unroll
        for (int r = 0; r < 4; ++r) {
          int sr = r * 16 + g;
          if (sr < 50) {
            int s = w * 50 + sr;
            const _Float16* row = mb + (size_t)s * 512 + c * 128;
            float e = 0.f;
#pragma unroll
            for (int k = 0; k < 16; ++k)
              e = dot8(*(const h8*)(row + k * 8), *(const h8*)&hh[c * 128 + k * 8], e);
            e += __shfl_xor(e, 1);
            e += __shfl_xor(e, 2);
            if (c == 0) {
              if (mask[q * 400 + s] == 0) e = -NEGF;
              es[s] = e;
            }
          }
        }
      }
      __syncthreads();
      if (t < 400) e_out[obase + t] = es[t];

      // softmax over es[400]
      float v = (t < 400) ? es[t] : -3.4e38f;
      float m = v;
#pragma unroll
      for (int o = 32; o; o >>= 1) m = fmaxf(m, __shfl_xor(m, o));
      if (l == 0) red[w] = m;
      __syncthreads();
      m = red[0];
#pragma unroll
      for (int qq = 1; qq < 8; ++qq) m = fmaxf(m, red[qq]);
      float p = (t < 400) ? expf(v - m) : 0.f;
      float sum = p;
#pragma unroll
      for (int o = 32; o; o >>= 1) sum += __shfl_xor(sum, o);
      if (l == 0) red[8 + w] = sum;
      __syncthreads();
      float tot = red[8];
#pragma unroll
      for (int qq = 9; qq < 16; ++qq) tot += red[qq];
      float inv = 1.f / tot;
      float aval = p * inv;
      if (t < 400) {
        es[t] = aval;                       // normalized attn for ctx pass
        a_out[obase + t] = aval;
        c_out[obase + t] = cum[t];          // coverage (pre-update)
        cum[t] += aval;
      }
      __syncthreads();

      // context: thread t owns dim t; 4 independent accumulators, 16 loads in flight
      float a0 = 0.f, a1 = 0.f, a2 = 0.f, a3 = 0.f;
#pragma unroll 4
      for (int si = 0; si < 400; si += 4) {
        a0 += es[si + 0] * (float)mb[(size_t)(si + 0) * 512 + t];
        a1 += es[si + 1] * (float)mb[(size_t)(si + 1) * 512 + t];
        a2 += es[si + 2] * (float)mb[(size_t)(si + 2) * 512 + t];
        a3 += es[si + 3] * (float)mb[(size_t)(si + 3) * 512 + t];
      }
      float acc2 = (a0 + a1) + (a2 + a3);
      unsigned cu = f16bits(acc2);
      unsigned other = __shfl_xor(cu, 1);
      if (!(t & 1)) {
        unsigned pack = cu | (other << 16);
        int kg = 512 + t;
        unsigned* dst = (unsigned*)((char*)(HCzT + (size_t)(ts + 1) * 32768)
                                    + (((kg >> 3) * 32 + q) << 4) + ((kg & 7) << 1));
        ASTORE32(dst, pack);
        *(unsigned*)(HC_A + ((size_t)ts * 32 + q) * 1024 + kg) = pack;
      }
    }
    gbar(bar, 2 * ts + 2);
  }
}

// ---------------- pointer scatter-max patch ----------------
__global__ __launch_bounds__(512) void pointer_kernel(
    const int* __restrict__ ext, const float* __restrict__ energ, float* __restrict__ logits)
{
  __shared__ int ids[400];
  __shared__ float es[400];
  int tb = blockIdx.x;
  int b = tb & 31;
  int tt = tb >> 5;
  int t = threadIdx.x;
  if (t < 400) {
    ids[t] = ext[b * 400 + t];
    es[t] = energ[(size_t)tt * 12800 + b * 400 + t];
  }
  __syncthreads();
  if (t < 400) {
    int id = ids[t];
    bool first = true;
    for (int s = 0; s < t; ++s) if (ids[s] == id) { first = false; break; }
    if (first) {
      float mx = es[t];
      for (int s = t + 1; s < 400; ++s) if (ids[s] == id) mx = fmaxf(mx, es[s]);
      if (mx != -NEGF) {
        float* p = &logits[(size_t)tb * 45050 + id];
        float base = 0.f;
        if (id < 45000) { float cur = *p; base = (cur == -NEGF) ? 0.f : cur; }
        float nv = base + mx;
        *p = (nv == 0.f) ? -NEGF : nv;
      }
    }
  }
}

// ---------------- host launcher ----------------
extern "C" void kernel_launch(void* const* d_in, const int* in_sizes, int n_in,
                              void* d_out, int out_size, void* d_ws, size_t ws_size,
                              hipStream_t stream) {
  const float* trg   = (const float*)d_in[0];
  const int*   ext   = (const int*)d_in[1];
  const float* inits = (const float*)d_in[2];
  const float* enc   = (const float*)d_in[3];
  const int*   mask  = (const int*)d_in[4];
  const float* W_enc = (const float*)d_in[5];
  const float* b_enc = (const float*)d_in[6];
  const float* W_red = (const float*)d_in[7];
  const float* b_red = (const float*)d_in[8];
  const float* W_ih  = (const float*)d_in[9];
  const float* W_hh  = (const float*)d_in[10];
  const float* b_ih  = (const float*)d_in[11];
  const float* b_hh  = (const float*)d_in[12];
  const float* W_cat = (const float*)d_in[13];
  const float* b_cat = (const float*)d_in[14];
  const float* W_log = (const float*)d_in[15];
  const float* b_log = (const float*)d_in[16];

  float* out = (float*)d_out;
  float* out_logits = out;                       // [1024 x 45050]
  float* out_attn   = out + 46131200;
  float* out_cov    = out_attn + 409600;
  float* out_energy = out_cov + 409600;

  char* ws = (char*)d_ws;
  size_t o = 0;
  auto alloc = [&](size_t bytes) { void* p = ws + o; o += (bytes + 255) & ~(size_t)255; return p; };
  _Float16* mem_h   = (_Float16*)alloc(12800ULL * 512 * 2);
  _Float16* enc_h   = (_Float16*)alloc(12800ULL * 512 * 2);
  _Float16* W_enc_h = (_Float16*)alloc(512ULL * 512 * 2);
  _Float16* emb_h   = (_Float16*)alloc(1024ULL * 320 * 2);
  _Float16* Wr1_h   = (_Float16*)alloc(384ULL * 320 * 2);
  _Float16* X1_h    = (_Float16*)alloc(1024ULL * 320 * 2);
  _Float16* W_ih_h  = (_Float16*)alloc(2048ULL * 320 * 2);
  _Float16* Wr2T_h  = (_Float16*)alloc(512ULL * 320 * 2);
  _Float16* W_cat_h = (_Float16*)alloc(512ULL * 1024 * 2);
  _Float16* W_log_h = (_Float16*)alloc(45056ULL * 512 * 2);
  _Float16* A_log_h = (_Float16*)alloc(1024ULL * 512 * 2);
  _Float16* HCzT    = (_Float16*)alloc(33ULL * 32768 * 2);
  _Float16* HC_A    = (_Float16*)alloc(1024ULL * 1024 * 2);
  _Float16* Wz      = (_Float16*)alloc(2048ULL * 1024 * 2); // [Whh | M1]
  float* P        = (float*)alloc(1024ULL * 2048 * 4);
  float* bias_sum = (float*)alloc(2048ULL * 4);
  unsigned* bar   = (unsigned*)alloc(4096);

  // consolidated prologue (init + all casts) in one launch
  prep_kernel<<<SB9, 256, 0, stream>>>(
      inits, b_ih, b_hh, enc, W_enc, W_red, W_ih, W_cat, W_log, W_hh, trg,
      HCzT, bias_sum, X1_h, bar, enc_h, W_enc_h, Wr1_h, W_ih_h, W_cat_h,
      W_log_h, Wz, emb_h, Wr2T_h);

  // batched pre-GEMMs (grid = ntm*ntn, last arg = ntn)
  gemm_f16<1><<<400, 256, 0, stream>>>(enc_h, W_enc_h, nullptr, mem_h, b_enc, 512, 512, 512, 4);
  gemm_f16<1><<<24,  256, 0, stream>>>(emb_h, Wr1_h, nullptr, X1_h, b_red, 300, 320, 320, 3);
  gemm_f16<0><<<128, 256, 0, stream>>>(X1_h, W_ih_h, P, nullptr, bias_sum, 2048, 320, 2048, 16);
  gemm_f16<1><<<64,  256, 0, stream>>>(W_ih_h, Wr2T_h, nullptr, Wz + 512, nullptr, 512, 320, 1024, 4);

  // fused persistent recurrence (R12-proven)
  fused_loop<<<32, 512, 0, stream>>>(mem_h, HCzT, HC_A, Wz, P, inits, mask,
                                     out_energy, out_attn, out_cov, bar);

  // epilogue
  gemm_f16<2><<<32, 256, 0, stream>>>(HC_A, W_cat_h, nullptr, A_log_h, b_cat, 512, 1024, 512, 4);
  gemm_f16<3><<<2816, 256, 0, stream>>>(A_log_h, W_log_h, out_logits, nullptr, b_log, 45000, 512, 45050, 352);
  pointer_kernel<<<1024, 512, 0, stream>>>(ext, out_energy, out_logits);
}